// Round 5
// baseline (672.265 us; speedup 1.0000x reference)
//
#include <hip/hip_runtime.h>

// Problem constants (match reference)
#define CB   64
#define CS   512
#define CD   128
#define CH   4
#define CFF  512
#define CL   4
#define NEG_BIG -3.0e38f
#define SCALE 0.17677669529663687f   // 1/sqrt(32)
#define EXSC  0.25505654050961364f   // SCALE * log2(e)

typedef __attribute__((ext_vector_type(8))) short short8;
typedef __attribute__((ext_vector_type(4))) float f32x4;

static __device__ __forceinline__ unsigned short f2b(float f) {
  union { float f; unsigned int u; } v; v.f = f;
  unsigned int u = v.u;
  unsigned int r = (u + 0x7fffu + ((u >> 16) & 1u)) >> 16;  // RNE
  return (unsigned short)r;
}

// ---------------------------------------------------------------------------
// All weights fp32 -> bf16 in one launch. Block ranges align exactly with
// each tensor (1024 elements per block): 192 | 64 | 256 | 256 blocks.
// ---------------------------------------------------------------------------
__global__ void k_cvt_all(const float* __restrict__ inw, const float* __restrict__ outw,
                          const float* __restrict__ ffw1, const float* __restrict__ ffw2,
                          unsigned short* __restrict__ wq, unsigned short* __restrict__ wo,
                          unsigned short* __restrict__ w1, unsigned short* __restrict__ w2) {
  int bid = blockIdx.x;
  const float* src; unsigned short* dst; int base;
  if (bid < 192)      { src = inw;  dst = wq; base = bid; }
  else if (bid < 256) { src = outw; dst = wo; base = bid - 192; }
  else if (bid < 512) { src = ffw1; dst = w1; base = bid - 256; }
  else                { src = ffw2; dst = w2; base = bid - 512; }
  int i = base * 256 + threadIdx.x;
  float4 v = ((const float4*)src)[i];
  ((ushort4*)dst)[i] = make_ushort4(f2b(v.x), f2b(v.y), f2b(v.z), f2b(v.w));
}

// ---------------------------------------------------------------------------
// Embedding + feature overrides; writes fp32 and bf16 copies of feat.
// ---------------------------------------------------------------------------
__global__ void k_embed(const int* __restrict__ tok, const int* __restrict__ picked,
                        const int* __restrict__ skipped, const int* __restrict__ nupg,
                        const float* __restrict__ emb, float* __restrict__ featf,
                        unsigned short* __restrict__ featb) {
  int idx = blockIdx.x * 256 + threadIdx.x;   // over B*S*32 float4
  int tp = idx >> 5, c4 = idx & 31;
  int t = tok[tp];
  float4 v = ((const float4*)emb)[t * 32 + c4];
  if (c4 == 0) {
    int b = tp >> 9, s = tp & 511;
    int nc = picked[b] + skipped[b];
    v.x = (s >= nc) ? 1.f : 0.f;
    v.y = (nupg[tp] > 0) ? 1.f : 0.f;
  }
  ((float4*)featf)[idx] = v;
  ((ushort4*)featb)[idx] = make_ushort4(f2b(v.x), f2b(v.y), f2b(v.z), f2b(v.w));
}

// ---------------------------------------------------------------------------
// Register-direct MFMA GEMM (K=128): C[M,NTOT] = A[M,128] @ W[NTOT,128]^T.
// No LDS staging: the 16x16x32 A/B fragment (lane l&15 row, 8 contiguous bf16
// at k-offset 8*(l>>4)) IS a coalesced 16B global load from row-major data.
// Any HW k-permutation applies identically to A and B -> cancels in the dot.
// 4 waves 2x2, 64x64 per wave; no barriers in the K-loop.
// EPI: 0 = +bias -> bf16 store; 2 = +bias +residual -> LN -> fp32+bf16 store.
// ---------------------------------------------------------------------------
template <int NTOT, int EPI>
__global__ __launch_bounds__(256, 2) void k_gemm_reg(
    const unsigned short* __restrict__ A, const unsigned short* __restrict__ W,
    const float* __restrict__ bias, float* __restrict__ outf,
    unsigned short* __restrict__ outb, const float* __restrict__ resf,
    const float* __restrict__ gam, const float* __restrict__ bet) {
  const int tid = threadIdx.x;
  const int m0 = blockIdx.x * 128, n0 = blockIdx.y * 128;
  const int lane = tid & 63, wid = tid >> 6;
  const int wm = wid >> 1, wn = wid & 1;
  const int lg = lane >> 4, r = lane & 15;

  f32x4 acc[4][4];
#pragma unroll
  for (int mi = 0; mi < 4; ++mi)
#pragma unroll
    for (int ni = 0; ni < 4; ++ni) acc[mi][ni] = (f32x4){0.f, 0.f, 0.f, 0.f};

  const unsigned short* Ab = A + (size_t)(m0 + wm * 64 + r) * 128 + lg * 8;
  const unsigned short* Wb = W + (size_t)(n0 + wn * 64 + r) * 128 + lg * 8;
#pragma unroll
  for (int kc = 0; kc < 4; ++kc) {
    short8 af[4], wf[4];
#pragma unroll
    for (int mi = 0; mi < 4; ++mi)
      af[mi] = *(const short8*)(Ab + mi * 2048 + kc * 32);
#pragma unroll
    for (int ni = 0; ni < 4; ++ni)
      wf[ni] = *(const short8*)(Wb + ni * 2048 + kc * 32);
#pragma unroll
    for (int mi = 0; mi < 4; ++mi)
#pragma unroll
      for (int ni = 0; ni < 4; ++ni)
        acc[mi][ni] = __builtin_amdgcn_mfma_f32_16x16x32_bf16(
            af[mi], wf[ni], acc[mi][ni], 0, 0, 0);
  }

  if constexpr (EPI == 0) {
#pragma unroll
    for (int mi = 0; mi < 4; ++mi)
#pragma unroll
      for (int ni = 0; ni < 4; ++ni) {
        int colg = n0 + wn * 64 + ni * 16 + r;
        float bia = bias[colg];
#pragma unroll
        for (int reg = 0; reg < 4; ++reg) {
          int rowg = m0 + wm * 64 + mi * 16 + 4 * lg + reg;
          outb[(size_t)rowg * NTOT + colg] = f2b(acc[mi][ni][reg] + bia);
        }
      }
  } else {
    // +bias +residual -> LayerNorm -> dual store (fp32 + bf16). NTOT == 128.
    __shared__ __align__(16) float Y[128 * 132];
#pragma unroll
    for (int mi = 0; mi < 4; ++mi)
#pragma unroll
      for (int ni = 0; ni < 4; ++ni) {
        int col = wn * 64 + ni * 16 + r;
        float bia = bias[col];
#pragma unroll
        for (int reg = 0; reg < 4; ++reg) {
          int row = wm * 64 + mi * 16 + 4 * lg + reg;
          Y[row * 132 + col] =
              acc[mi][ni][reg] + bia + resf[(size_t)(m0 + row) * 128 + col];
        }
      }
    __syncthreads();
    const int rr = tid >> 1, qq = tid & 1;  // 2 lanes per row, 64 cols each
    float sum = 0.f, sum2 = 0.f;
    float4 yv[16];
#pragma unroll
    for (int c = 0; c < 16; ++c) {
      float4 y = *(const float4*)&Y[rr * 132 + qq * 64 + c * 4];
      yv[c] = y;
      sum += y.x + y.y + y.z + y.w;
      sum2 += y.x * y.x + y.y * y.y + y.z * y.z + y.w * y.w;
    }
    sum += __shfl_xor(sum, 1);
    sum2 += __shfl_xor(sum2, 1);
    const float mean = sum * (1.f / 128.f);
    const float var = sum2 * (1.f / 128.f) - mean * mean;
    const float rstd = rsqrtf(var + 1e-5f);
#pragma unroll
    for (int c = 0; c < 16; ++c) {
      float4 gv = ((const float4*)gam)[qq * 16 + c];
      float4 bv = ((const float4*)bet)[qq * 16 + c];
      float4 y = yv[c];
      y.x = (y.x - mean) * rstd * gv.x + bv.x;
      y.y = (y.y - mean) * rstd * gv.y + bv.y;
      y.z = (y.z - mean) * rstd * gv.z + bv.z;
      y.w = (y.w - mean) * rstd * gv.w + bv.w;
      ((float4*)outf)[(size_t)(m0 + rr) * 32 + qq * 16 + c] = y;
      *(ushort4*)&outb[(size_t)(m0 + rr) * 128 + qq * 64 + c * 4] =
          make_ushort4(f2b(y.x), f2b(y.y), f2b(y.z), f2b(y.w));
    }
  }
}

// ---------------------------------------------------------------------------
// MFMA flash attention, fixed-max softmax. Grid = CB*CH*2; block = (b,h,half):
// 4 waves x 64 q-rows. K [j] rows at stride 40 ushorts (phase-slot base
// 20r mod 32 covers all 8 slots -> conflict-free b128 reads). V^T [d][j]
// XOR-swizzled ((row*2)^((d&7)<<4)): each 8-lane phase covers 8 distinct 16B
// slots -> conflict-free. Scores tiny by construction (|s|<1, huge margin):
// p = exp2(min(s*SCALE*log2e, 43)) with no running max; masked lanes
// exp(NEG_BIG) = 0 exactly. Row sums via MFMA against all-ones B
// (permutation-proof). P roundtrips a per-wave LDS tile (stride 40).
// ---------------------------------------------------------------------------
__global__ __launch_bounds__(256, 2) void k_attn_mfma(
    const unsigned short* __restrict__ qkvb, const int* __restrict__ npadp,
    const int* __restrict__ picked, const int* __restrict__ skipped,
    unsigned short* __restrict__ obufb) {
  __shared__ __align__(16) unsigned short Ks[CS * 40];   // 40KB [j][d] pad
  __shared__ __align__(16) unsigned short Vt[32 * CS];   // 32KB [d][j] swz
  __shared__ __align__(16) unsigned short Ps[4][16 * 40];// 5KB per-wave P
  const int bh = blockIdx.x >> 1, half = blockIdx.x & 1;
  const int b = bh >> 2, h = bh & 3;
  const int tid = threadIdx.x;
  const unsigned short* base = qkvb + (size_t)b * CS * 384;
#pragma unroll
  for (int i = 0; i < 8; ++i) {
    int f = tid + i * 256;
    int row = f >> 2, c = f & 3;
    *(uint4*)&Ks[row * 40 + c * 8] =
        *(const uint4*)(base + row * 384 + 128 + h * 32 + c * 8);
    short8 vv = *(const short8*)(base + row * 384 + 256 + h * 32 + c * 8);
#pragma unroll
    for (int e = 0; e < 8; ++e) {
      int d = c * 8 + e;
      *(unsigned short*)((char*)Vt + d * 1024 + ((row * 2) ^ ((d & 7) << 4))) =
          (unsigned short)vv[e];
    }
  }
  __syncthreads();
  const int lane = tid & 63, w = tid >> 6;
  const int lg = lane >> 4, r = lane & 15;
  const int npd = npadp[b];
  const int jhi_mid = CS - (picked[b] + skipped[b]);
  unsigned short* Pw = &Ps[w][0];
  short8 onesf;
#pragma unroll
  for (int e = 0; e < 8; ++e) onesf[e] = (short)0x3F80;  // bf16 1.0

  for (int qt = 0; qt < 4; ++qt) {
    const int m0q = half * 256 + w * 64 + qt * 16;
    short8 qf = *(const short8*)(base + (size_t)(m0q + r) * 384 + h * 32 + 8 * lg);
    f32x4 accO0 = (f32x4){0.f, 0.f, 0.f, 0.f};
    f32x4 accO1 = (f32x4){0.f, 0.f, 0.f, 0.f};
    f32x4 accL  = (f32x4){0.f, 0.f, 0.f, 0.f};
    int jlo[4], jhi[4];
#pragma unroll
    for (int g = 0; g < 4; ++g) {
      int m = m0q + 4 * lg + g;
      if (m < npd) { jlo[g] = m; jhi[g] = m + 1; }
      else         { jlo[g] = npd; jhi[g] = (m < jhi_mid) ? jhi_mid : CS; }
    }
    for (int jc = 0; jc < 16; ++jc) {
      const int j0 = jc * 32;
      short8 kf0 = *(const short8*)&Ks[(j0 + r) * 40 + 8 * lg];
      short8 kf1 = *(const short8*)&Ks[(j0 + 16 + r) * 40 + 8 * lg];
      f32x4 z = (f32x4){0.f, 0.f, 0.f, 0.f};
      f32x4 s0 = __builtin_amdgcn_mfma_f32_16x16x32_bf16(qf, kf0, z, 0, 0, 0);
      f32x4 s1 = __builtin_amdgcn_mfma_f32_16x16x32_bf16(qf, kf1, z, 0, 0, 0);
      const int ja = j0 + r, jb = j0 + 16 + r;
#pragma unroll
      for (int g = 0; g < 4; ++g) {
        float t0 = (ja >= jlo[g] && ja < jhi[g]) ? s0[g] * EXSC : NEG_BIG;
        float t1 = (jb >= jlo[g] && jb < jhi[g]) ? s1[g] * EXSC : NEG_BIG;
        float p0 = exp2f(fminf(t0, 43.f));
        float p1 = exp2f(fminf(t1, 43.f));
        Pw[(4 * lg + g) * 40 + r]      = f2b(p0);
        Pw[(4 * lg + g) * 40 + 16 + r] = f2b(p1);
      }
      short8 pa = *(const short8*)&Pw[r * 40 + 8 * lg];
      const int jby = ((j0 + 8 * lg) * 2) ^ ((r & 7) << 4);
      short8 vf0 = *(const short8*)((const char*)Vt + r * 1024 + jby);
      short8 vf1 = *(const short8*)((const char*)Vt + (16 + r) * 1024 + jby);
      accL  = __builtin_amdgcn_mfma_f32_16x16x32_bf16(pa, onesf, accL, 0, 0, 0);
      accO0 = __builtin_amdgcn_mfma_f32_16x16x32_bf16(pa, vf0, accO0, 0, 0, 0);
      accO1 = __builtin_amdgcn_mfma_f32_16x16x32_bf16(pa, vf1, accO1, 0, 0, 0);
    }
#pragma unroll
    for (int g = 0; g < 4; ++g) {
      float inv = 1.f / accL[g];
      int m = m0q + 4 * lg + g;
      unsigned short* op = obufb + ((size_t)(b * CS + m) * CD + h * 32);
      op[r]      = f2b(accO0[g] * inv);
      op[16 + r] = f2b(accO1[g] * inv);
    }
  }
}

// ---------------------------------------------------------------------------
// Fused FFN, register-direct: feat = LN2(x + relu(x@W1^T+b1)@W2^T + b2).
// BM=64, grid 512 (2 blocks/CU). x/W1/W2 fragments loaded straight from
// global; LDS only for the h C-layout -> A-layout exchange (stride 72
// ushorts: phase-slot base 4r mod 32 -> 8 distinct slots, conflict-free)
// and the LN Y tile.
// ---------------------------------------------------------------------------
__global__ __launch_bounds__(256, 2) void k_ffn_reg(
    const unsigned short* __restrict__ x, const unsigned short* __restrict__ w1b,
    const float* __restrict__ b1, const unsigned short* __restrict__ w2b,
    const float* __restrict__ b2, const float* __restrict__ gam,
    const float* __restrict__ bet, float* __restrict__ featf,
    unsigned short* __restrict__ featb) {
  __shared__ __align__(16) unsigned short hs[64 * 72];   // 9.2KB
  __shared__ __align__(16) float Y[64 * 132];            // 33.8KB
  const int tid = threadIdx.x;
  const int m0 = blockIdx.x * 64;
  const int lane = tid & 63, w = tid >> 6;
  const int wm = w >> 1, wn = w & 1;
  const int lg = lane >> 4, r = lane & 15;

  f32x4 accO[2][4];
#pragma unroll
  for (int mi = 0; mi < 2; ++mi)
#pragma unroll
    for (int ni = 0; ni < 4; ++ni) accO[mi][ni] = (f32x4){0.f, 0.f, 0.f, 0.f};

  const unsigned short* xb = x + (size_t)(m0 + wm * 32 + r) * 128 + lg * 8;
  const unsigned short* w2p = w2b + (size_t)(wn * 64 + r) * 512 + lg * 8;
  const unsigned short* hp = &hs[(wm * 32 + r) * 72 + lg * 8];

  for (int cc = 0; cc < 8; ++cc) {
    // FF1: h[64m x 64n] = relu(x @ W1c^T + b1c); wave tile 32m x 32n
    f32x4 accH[2][2];
#pragma unroll
    for (int mi = 0; mi < 2; ++mi)
#pragma unroll
      for (int ni = 0; ni < 2; ++ni) accH[mi][ni] = (f32x4){0.f, 0.f, 0.f, 0.f};
    const unsigned short* w1p =
        w1b + (size_t)(cc * 64 + wn * 32 + r) * 128 + lg * 8;
#pragma unroll
    for (int kc = 0; kc < 4; ++kc) {
      short8 af[2], wf[2];
#pragma unroll
      for (int mi = 0; mi < 2; ++mi)
        af[mi] = *(const short8*)(xb + mi * 2048 + kc * 32);
#pragma unroll
      for (int ni = 0; ni < 2; ++ni)
        wf[ni] = *(const short8*)(w1p + ni * 2048 + kc * 32);
#pragma unroll
      for (int mi = 0; mi < 2; ++mi)
#pragma unroll
        for (int ni = 0; ni < 2; ++ni)
          accH[mi][ni] = __builtin_amdgcn_mfma_f32_16x16x32_bf16(
              af[mi], wf[ni], accH[mi][ni], 0, 0, 0);
    }
    __syncthreads();  // previous FF2 reads of hs complete
#pragma unroll
    for (int ni = 0; ni < 2; ++ni) {
      int n = wn * 32 + ni * 16 + r;
      float bv = b1[cc * 64 + n];
#pragma unroll
      for (int mi = 0; mi < 2; ++mi)
#pragma unroll
        for (int g = 0; g < 4; ++g) {
          int m = wm * 32 + mi * 16 + 4 * lg + g;
          hs[m * 72 + n] = f2b(fmaxf(accH[mi][ni][g] + bv, 0.f));
        }
    }
    __syncthreads();
    // FF2: accO += h @ W2c^T; wave tile 32m x 64n; k = 64
#pragma unroll
    for (int kc2 = 0; kc2 < 2; ++kc2) {
      short8 af[2], wf[4];
#pragma unroll
      for (int mi = 0; mi < 2; ++mi)
        af[mi] = *(const short8*)(hp + mi * 1152 + kc2 * 32);
#pragma unroll
      for (int ni = 0; ni < 4; ++ni)
        wf[ni] = *(const short8*)(w2p + ni * 8192 + cc * 64 + kc2 * 32);
#pragma unroll
      for (int mi = 0; mi < 2; ++mi)
#pragma unroll
        for (int ni = 0; ni < 4; ++ni)
          accO[mi][ni] = __builtin_amdgcn_mfma_f32_16x16x32_bf16(
              af[mi], wf[ni], accO[mi][ni], 0, 0, 0);
    }
  }
  // Epilogue: +b2 +residual -> LN -> dual store
#pragma unroll
  for (int mi = 0; mi < 2; ++mi)
#pragma unroll
    for (int ni = 0; ni < 4; ++ni) {
      int col = wn * 64 + ni * 16 + r;
      float bv = b2[col];
#pragma unroll
      for (int g = 0; g < 4; ++g) {
        int row = wm * 32 + mi * 16 + 4 * lg + g;
        Y[row * 132 + col] =
            accO[mi][ni][g] + bv + featf[(size_t)(m0 + row) * 128 + col];
      }
    }
  __syncthreads();
  const int rr = tid >> 2, qq = tid & 3;  // 4 lanes per row, 32 cols each
  float sum = 0.f, sum2 = 0.f;
  float4 yv[8];
#pragma unroll
  for (int c = 0; c < 8; ++c) {
    float4 y = *(const float4*)&Y[rr * 132 + qq * 32 + c * 4];
    yv[c] = y;
    sum += y.x + y.y + y.z + y.w;
    sum2 += y.x * y.x + y.y * y.y + y.z * y.z + y.w * y.w;
  }
  sum += __shfl_xor(sum, 1); sum += __shfl_xor(sum, 2);
  sum2 += __shfl_xor(sum2, 1); sum2 += __shfl_xor(sum2, 2);
  const float mean = sum * (1.f / 128.f);
  const float var = sum2 * (1.f / 128.f) - mean * mean;
  const float rstd = rsqrtf(var + 1e-5f);
#pragma unroll
  for (int c = 0; c < 8; ++c) {
    float4 gv = ((const float4*)gam)[qq * 8 + c];
    float4 bv = ((const float4*)bet)[qq * 8 + c];
    float4 y = yv[c];
    y.x = (y.x - mean) * rstd * gv.x + bv.x;
    y.y = (y.y - mean) * rstd * gv.y + bv.y;
    y.z = (y.z - mean) * rstd * gv.z + bv.z;
    y.w = (y.w - mean) * rstd * gv.w + bv.w;
    ((float4*)featf)[(size_t)(m0 + rr) * 32 + qq * 8 + c] = y;
    *(ushort4*)&featb[(size_t)(m0 + rr) * 128 + qq * 32 + c * 4] =
        make_ushort4(f2b(y.x), f2b(y.y), f2b(y.z), f2b(y.w));
  }
}

// ---------------------------------------------------------------------------
// Final projection (DIM -> 2) + softmax. 4 lanes per token.
// ---------------------------------------------------------------------------
__global__ void k_final(const float* __restrict__ feat, const float* __restrict__ pw,
                        const float* __restrict__ pb, float* __restrict__ out) {
  const int tid = threadIdx.x;
  const int tokb = blockIdx.x * 64 + (tid >> 2);
  const int qq = tid & 3;
  float d0 = 0.f, d1 = 0.f;
#pragma unroll
  for (int c = 0; c < 8; ++c) {
    float4 xv = ((const float4*)feat)[tokb * 32 + qq * 8 + c];
    float4 w0 = ((const float4*)pw)[qq * 8 + c];
    float4 w1 = ((const float4*)pw)[32 + qq * 8 + c];
    d0 += xv.x * w0.x + xv.y * w0.y + xv.z * w0.z + xv.w * w0.w;
    d1 += xv.x * w1.x + xv.y * w1.y + xv.z * w1.z + xv.w * w1.w;
  }
  d0 += __shfl_xor(d0, 1); d0 += __shfl_xor(d0, 2);
  d1 += __shfl_xor(d1, 1); d1 += __shfl_xor(d1, 2);
  if (qq == 0) {
    float l0 = d0 + pb[0], l1 = d1 + pb[1];
    float mx = fmaxf(l0, l1);
    float e0 = __expf(l0 - mx), e1 = __expf(l1 - mx);
    float inv = 1.f / (e0 + e1);
    ((float2*)out)[tokb] = make_float2(e0 * inv, e1 * inv);
  }
}

// ---------------------------------------------------------------------------
extern "C" void kernel_launch(void* const* d_in, const int* in_sizes, int n_in,
                              void* d_out, int out_size, void* d_ws, size_t ws_size,
                              hipStream_t stream) {
  const int* tok     = (const int*)d_in[0];
  const int* npad    = (const int*)d_in[1];
  const int* picked  = (const int*)d_in[2];
  const int* skipped = (const int*)d_in[3];
  const int* nupg    = (const int*)d_in[4];
  const float* emb   = (const float*)d_in[5];
  const float* inw   = (const float*)d_in[6];
  const float* inb   = (const float*)d_in[7];
  const float* outw  = (const float*)d_in[8];
  const float* outb_ = (const float*)d_in[9];
  const float* g1    = (const float*)d_in[10];
  const float* b1    = (const float*)d_in[11];
  const float* ffw1  = (const float*)d_in[12];
  const float* ffb1  = (const float*)d_in[13];
  const float* ffw2  = (const float*)d_in[14];
  const float* ffb2  = (const float*)d_in[15];
  const float* g2    = (const float*)d_in[16];
  const float* b2    = (const float*)d_in[17];
  const float* pw    = (const float*)d_in[18];
  const float* pb    = (const float*)d_in[19];

  char* wsb = (char*)d_ws;
  float*          featf = (float*)(wsb);                       // 16 MB
  unsigned short* qkvb  = (unsigned short*)(wsb + 16777216);   // 24 MB
  unsigned short* featb = (unsigned short*)(wsb + 41943040);   // 8 MB
  unsigned short* obufb = (unsigned short*)(wsb + 50331648);   // 8 MB
  unsigned short* wqkvb = (unsigned short*)(wsb + 58720256);   // 384 KB
  unsigned short* woutb = (unsigned short*)(wsb + 59113472);   // 128 KB
  unsigned short* wff1b = (unsigned short*)(wsb + 59244544);   // 512 KB
  unsigned short* wff2b = (unsigned short*)(wsb + 59768832);   // 512 KB

  // All weights -> bf16, one launch (graph-safe, deterministic)
  k_cvt_all<<<dim3(768), 256, 0, stream>>>(inw, outw, ffw1, ffw2,
                                           wqkvb, woutb, wff1b, wff2b);

  k_embed<<<dim3(CB * CS * 32 / 256), 256, 0, stream>>>(
      tok, picked, skipped, nupg, emb, featf, featb);

  for (int l = 0; l < CL; ++l) {
    k_gemm_reg<384, 0><<<dim3(256, 3), 256, 0, stream>>>(
        featb, wqkvb + (size_t)l * 49152, inb + (size_t)l * 384,
        nullptr, qkvb, nullptr, nullptr, nullptr);
    k_attn_mfma<<<dim3(CB * CH * 2), 256, 0, stream>>>(
        qkvb, npad, picked, skipped, obufb);
    k_gemm_reg<128, 2><<<dim3(256, 1), 256, 0, stream>>>(
        obufb, woutb + (size_t)l * 16384, outb_ + (size_t)l * 128,
        featf, featb, featf, g1 + (size_t)l * 128, b1 + (size_t)l * 128);
    k_ffn_reg<<<dim3(512), 256, 0, stream>>>(
        featb, wff1b + (size_t)l * 65536, ffb1 + (size_t)l * 512,
        wff2b + (size_t)l * 65536, ffb2 + (size_t)l * 128,
        g2 + (size_t)l * 128, b2 + (size_t)l * 128, featf, featb);
  }

  k_final<<<dim3(CB * CS / 64), 256, 0, stream>>>(featf, pw, pb, (float*)d_out);
}

// Round 7
// 601.632 us; speedup vs baseline: 1.1174x; 1.1174x over previous
//
#include <hip/hip_runtime.h>

// Problem constants (match reference)
#define CB   64
#define CS   512
#define CD   128
#define CH   4
#define CFF  512
#define CL   4
#define NEG_BIG -3.0e38f
#define SCALE 0.17677669529663687f   // 1/sqrt(32)
#define EXSC  0.25505654050961364f   // SCALE * log2(e)

typedef __attribute__((ext_vector_type(8))) short short8;
typedef __attribute__((ext_vector_type(4))) float f32x4;
typedef __attribute__((ext_vector_type(4))) unsigned int u32x4;

static __device__ __forceinline__ unsigned short f2b(float f) {
  union { float f; unsigned int u; } v; v.f = f;
  unsigned int u = v.u;
  unsigned int r = (u + 0x7fffu + ((u >> 16) & 1u)) >> 16;  // RNE
  return (unsigned short)r;
}

// ---------------------------------------------------------------------------
// All weights fp32 -> bf16 in one launch (block ranges: 192 | 64 | 256 | 256).
// ---------------------------------------------------------------------------
__global__ void k_cvt_all(const float* __restrict__ inw, const float* __restrict__ outw,
                          const float* __restrict__ ffw1, const float* __restrict__ ffw2,
                          unsigned short* __restrict__ wq, unsigned short* __restrict__ wo,
                          unsigned short* __restrict__ w1, unsigned short* __restrict__ w2) {
  int bid = blockIdx.x;
  const float* src; unsigned short* dst; int base;
  if (bid < 192)      { src = inw;  dst = wq; base = bid; }
  else if (bid < 256) { src = outw; dst = wo; base = bid - 192; }
  else if (bid < 512) { src = ffw1; dst = w1; base = bid - 256; }
  else                { src = ffw2; dst = w2; base = bid - 512; }
  int i = base * 256 + threadIdx.x;
  float4 v = ((const float4*)src)[i];
  ((ushort4*)dst)[i] = make_ushort4(f2b(v.x), f2b(v.y), f2b(v.z), f2b(v.w));
}

// ---------------------------------------------------------------------------
// Embedding + feature overrides; fp32 + bf16 copies of feat.
// ---------------------------------------------------------------------------
__global__ void k_embed(const int* __restrict__ tok, const int* __restrict__ picked,
                        const int* __restrict__ skipped, const int* __restrict__ nupg,
                        const float* __restrict__ emb, float* __restrict__ featf,
                        unsigned short* __restrict__ featb) {
  int idx = blockIdx.x * 256 + threadIdx.x;   // over B*S*32 float4
  int tp = idx >> 5, c4 = idx & 31;
  int t = tok[tp];
  float4 v = ((const float4*)emb)[t * 32 + c4];
  if (c4 == 0) {
    int b = tp >> 9, s = tp & 511;
    int nc = picked[b] + skipped[b];
    v.x = (s >= nc) ? 1.f : 0.f;
    v.y = (nupg[tp] > 0) ? 1.f : 0.f;
  }
  ((float4*)featf)[idx] = v;
  ((ushort4*)featb)[idx] = make_ushort4(f2b(v.x), f2b(v.y), f2b(v.z), f2b(v.w));
}

// ---------------------------------------------------------------------------
// QKV GEMM, register-direct, head-major outputs:
//  y=0: Q -> qb[b][h][s][32], scaled by EXSC (folds softmax scale + log2e)
//  y=1: K -> kb[b][h][s][32]
//  y=2: V -> vtb[b][h][32][512] transposed, with j-permutation within each
//       32-token chunk: token jl stored at p = 8*((jl&15)>>2) + 4*(jl>>4) +
//       (jl&3), so attention's PV B-fragment (k-map 4lg+(e&3)+16(e>>2)) is a
//       single contiguous b128 read. 4-reg packs stay contiguous (8B stores).
// ---------------------------------------------------------------------------
__global__ __launch_bounds__(256, 2) void k_gemm_qkv(
    const unsigned short* __restrict__ A, const unsigned short* __restrict__ W,
    const float* __restrict__ bias, unsigned short* __restrict__ qb,
    unsigned short* __restrict__ kb, unsigned short* __restrict__ vtb) {
  const int tid = threadIdx.x;
  const int m0 = blockIdx.x * 128;
  const int y = blockIdx.y;           // 0=Q, 1=K, 2=V
  const int n0 = y * 128;
  const int lane = tid & 63, wid = tid >> 6;
  const int wm = wid >> 1, wn = wid & 1;
  const int lg = lane >> 4, r = lane & 15;

  f32x4 acc[4][4];
#pragma unroll
  for (int mi = 0; mi < 4; ++mi)
#pragma unroll
    for (int ni = 0; ni < 4; ++ni) acc[mi][ni] = (f32x4){0.f, 0.f, 0.f, 0.f};

  const unsigned short* Ab = A + (size_t)(m0 + wm * 64 + r) * 128 + lg * 8;
  const unsigned short* Wb = W + (size_t)(n0 + wn * 64 + r) * 128 + lg * 8;
#pragma unroll
  for (int kc = 0; kc < 4; ++kc) {
    short8 af[4], wf[4];
#pragma unroll
    for (int mi = 0; mi < 4; ++mi) af[mi] = *(const short8*)(Ab + mi * 2048 + kc * 32);
#pragma unroll
    for (int ni = 0; ni < 4; ++ni) wf[ni] = *(const short8*)(Wb + ni * 2048 + kc * 32);
#pragma unroll
    for (int mi = 0; mi < 4; ++mi)
#pragma unroll
      for (int ni = 0; ni < 4; ++ni)
        acc[mi][ni] = __builtin_amdgcn_mfma_f32_16x16x32_bf16(
            af[mi], wf[ni], acc[mi][ni], 0, 0, 0);
  }

  const int bidx = m0 >> 9;  // batch (128-row tiles never straddle b)
  if (y < 2) {
    unsigned short* dst = y ? kb : qb;
    const float sc = y ? 1.f : EXSC;
#pragma unroll
    for (int mi = 0; mi < 4; ++mi)
#pragma unroll
      for (int ni = 0; ni < 4; ++ni) {
        int cl = wn * 64 + ni * 16 + r;           // col within 128-section
        int h = cl >> 5, dd = cl & 31;
        float bia = bias[n0 + cl];
        unsigned short* dp =
            dst + ((size_t)(bidx * 4 + h) * 512) * 32 + dd;
#pragma unroll
        for (int reg = 0; reg < 4; ++reg) {
          int s = (m0 + wm * 64 + mi * 16 + 4 * lg + reg) & 511;
          dp[(size_t)s * 32] = f2b((acc[mi][ni][reg] + bia) * sc);
        }
      }
  } else {
#pragma unroll
    for (int mi = 0; mi < 4; ++mi)
#pragma unroll
      for (int ni = 0; ni < 4; ++ni) {
        int cl = wn * 64 + ni * 16 + r;
        int h = cl >> 5, dd = cl & 31;
        float bia = bias[256 + cl];
        int s4 = (m0 + wm * 64 + mi * 16 + 4 * lg) & 511;  // multiple of 4
        int chunk = s4 >> 5, jl = s4 & 31;
        int p = 8 * ((jl & 15) >> 2) + 4 * (jl >> 4);      // jl&3 == 0
        ushort4 pk = make_ushort4(
            f2b(acc[mi][ni][0] + bia), f2b(acc[mi][ni][1] + bia),
            f2b(acc[mi][ni][2] + bia), f2b(acc[mi][ni][3] + bia));
        *(ushort4*)&vtb[((size_t)(bidx * 4 + h) * 32 + dd) * 512 + chunk * 32 + p] = pk;
      }
  }
}

// ---------------------------------------------------------------------------
// Flash attention v2: one block per (b,h), 512 threads (8 waves x 64 q-rows).
// Swapped QK^T (mfma(K,Q)) keeps P per-lane for q = lane's r; PV pairs
// pa[e] <-> vf[e] with the SAME (lg,e)->j map (j = j0+4lg+(e&3)+16(e>>2)),
// so the unknown hardware k-map cancels. P packed in-register with f2b
// (verified primitive; replaces the round-6 cvt_pk asm — prime NaN suspect).
// Masks only at jc=0 (j>=npd) and jc=15 (j<jhi per lane); pad rows (q<npd,
// allowed={q}) are fixed up in the epilogue as O = V[q] exactly.
// ---------------------------------------------------------------------------
__global__ __launch_bounds__(512, 1) void k_attn2(
    const unsigned short* __restrict__ qb, const unsigned short* __restrict__ kb,
    const unsigned short* __restrict__ vtb, const int* __restrict__ npadp,
    const int* __restrict__ picked, const int* __restrict__ skipped,
    unsigned short* __restrict__ obufb) {
  __shared__ __align__(16) unsigned short Ks[CS * 40];   // 40KB
  __shared__ __align__(16) unsigned short Vt[32 * CS];   // 32KB
  const int bh = blockIdx.x, b = bh >> 2, h = bh & 3;
  const int tid = threadIdx.x;
  const unsigned short* qbp = qb + ((size_t)bh * 512) * 32;
  const unsigned short* kbp = kb + ((size_t)bh * 512) * 32;
  const unsigned short* vtp = vtb + ((size_t)bh * 32) * 512;
#pragma unroll
  for (int i = 0; i < 4; ++i) {
    int f = tid + i * 512;                       // [0, 2048)
    int row = f >> 2, c = f & 3;
    *(uint4*)&Ks[row * 40 + c * 8] = *(const uint4*)(kbp + row * 32 + c * 8);
    int rowd = f >> 6, c16 = f & 63;
    *(uint4*)((char*)Vt + rowd * 1024 + ((c16 * 16) ^ ((rowd & 7) << 4))) =
        *(const uint4*)(vtp + rowd * 512 + c16 * 8);
  }
  const int lane = tid & 63, w = tid >> 6;
  const int lg = lane >> 4, r = lane & 15;
  const int npd = npadp[b];
  const int jhi_mid = CS - (picked[b] + skipped[b]);
  short8 onesf;
#pragma unroll
  for (int e = 0; e < 8; ++e) onesf[e] = (short)0x3F80;  // bf16 1.0
  __syncthreads();

  short8 qf[4];
  int jhiR[4];
#pragma unroll
  for (int qt = 0; qt < 4; ++qt) {
    int q = w * 64 + qt * 16 + r;
    qf[qt] = *(const short8*)(qbp + (size_t)q * 32 + 8 * lg);
    jhiR[qt] = (q < jhi_mid) ? jhi_mid : CS;
  }
  f32x4 aO0[4], aO1[4], aL[4];
#pragma unroll
  for (int qt = 0; qt < 4; ++qt) {
    aO0[qt] = (f32x4){0.f, 0.f, 0.f, 0.f};
    aO1[qt] = (f32x4){0.f, 0.f, 0.f, 0.f};
    aL[qt]  = (f32x4){0.f, 0.f, 0.f, 0.f};
  }

  for (int jc = 0; jc < 16; ++jc) {
    const int j0 = jc * 32;
    short8 kf0 = *(const short8*)&Ks[(j0 + r) * 40 + 8 * lg];
    short8 kf1 = *(const short8*)&Ks[(j0 + 16 + r) * 40 + 8 * lg];
    const int jby = (j0 * 2 + 16 * lg) ^ ((r & 7) << 4);
    short8 vf0 = *(const short8*)((const char*)Vt + r * 1024 + jby);
    short8 vf1 = *(const short8*)((const char*)Vt + (16 + r) * 1024 + jby);
#pragma unroll
    for (int qt = 0; qt < 4; ++qt) {
      f32x4 z = (f32x4){0.f, 0.f, 0.f, 0.f};
      f32x4 s0 = __builtin_amdgcn_mfma_f32_16x16x32_bf16(kf0, qf[qt], z, 0, 0, 0);
      f32x4 s1 = __builtin_amdgcn_mfma_f32_16x16x32_bf16(kf1, qf[qt], z, 0, 0, 0);
      float p0[4], p1[4];
#pragma unroll
      for (int g = 0; g < 4; ++g) {
        p0[g] = exp2f(fminf(s0[g], 43.f));
        p1[g] = exp2f(fminf(s1[g], 43.f));
      }
      if (jc == 0) {
#pragma unroll
        for (int g = 0; g < 4; ++g)
          p0[g] = (4 * lg + g >= npd) ? p0[g] : 0.f;
      }
      if (jc == 15) {
#pragma unroll
        for (int g = 0; g < 4; ++g)
          p1[g] = (496 + 4 * lg + g < jhiR[qt]) ? p1[g] : 0.f;
      }
      // Pack P -> bf16 pairs with the verified f2b (element e of pa must be
      // P at j = j0 + 4*lg + (e&3) + 16*(e>>2); low half of each u32 = even e).
      unsigned int d0 = ((unsigned int)f2b(p0[1]) << 16) | f2b(p0[0]);
      unsigned int d1 = ((unsigned int)f2b(p0[3]) << 16) | f2b(p0[2]);
      unsigned int d2 = ((unsigned int)f2b(p1[1]) << 16) | f2b(p1[0]);
      unsigned int d3 = ((unsigned int)f2b(p1[3]) << 16) | f2b(p1[2]);
      u32x4 pd = (u32x4){d0, d1, d2, d3};
      short8 pa = __builtin_bit_cast(short8, pd);
      aL[qt]  = __builtin_amdgcn_mfma_f32_16x16x32_bf16(pa, onesf, aL[qt], 0, 0, 0);
      aO0[qt] = __builtin_amdgcn_mfma_f32_16x16x32_bf16(pa, vf0, aO0[qt], 0, 0, 0);
      aO1[qt] = __builtin_amdgcn_mfma_f32_16x16x32_bf16(pa, vf1, aO1[qt], 0, 0, 0);
    }
  }

#pragma unroll
  for (int qt = 0; qt < 4; ++qt)
#pragma unroll
    for (int g = 0; g < 4; ++g) {
      int qg = w * 64 + qt * 16 + 4 * lg + g;
      float inv = 1.f / aL[qt][g];
      unsigned short o0 = f2b(aO0[qt][g] * inv);
      unsigned short o1 = f2b(aO1[qt][g] * inv);
      if (qg < npd) {  // pad row: softmax over {qg} -> output = V[qg] exactly
        int p = 8 * (qg >> 2) + (qg & 3);  // qg < 16 -> chunk 0
        o0 = *(const unsigned short*)((const char*)Vt + r * 1024 +
                                      ((2 * p) ^ ((r & 7) << 4)));
        o1 = *(const unsigned short*)((const char*)Vt + (16 + r) * 1024 +
                                      ((2 * p) ^ ((r & 7) << 4)));
      }
      unsigned short* op = obufb + ((size_t)(b * 512 + qg)) * 128 + h * 32;
      op[r] = o0;
      op[16 + r] = o1;
    }
}

// ---------------------------------------------------------------------------
// Register-direct MFMA GEMM (K=128) with +bias +residual -> LN epilogue.
// ---------------------------------------------------------------------------
__global__ __launch_bounds__(256, 2) void k_gemm_ln(
    const unsigned short* __restrict__ A, const unsigned short* __restrict__ W,
    const float* __restrict__ bias, float* __restrict__ outf,
    unsigned short* __restrict__ outb, const float* __restrict__ resf,
    const float* __restrict__ gam, const float* __restrict__ bet) {
  const int tid = threadIdx.x;
  const int m0 = blockIdx.x * 128;
  const int lane = tid & 63, wid = tid >> 6;
  const int wm = wid >> 1, wn = wid & 1;
  const int lg = lane >> 4, r = lane & 15;

  f32x4 acc[4][4];
#pragma unroll
  for (int mi = 0; mi < 4; ++mi)
#pragma unroll
    for (int ni = 0; ni < 4; ++ni) acc[mi][ni] = (f32x4){0.f, 0.f, 0.f, 0.f};

  const unsigned short* Ab = A + (size_t)(m0 + wm * 64 + r) * 128 + lg * 8;
  const unsigned short* Wb = W + (size_t)(wn * 64 + r) * 128 + lg * 8;
#pragma unroll
  for (int kc = 0; kc < 4; ++kc) {
    short8 af[4], wf[4];
#pragma unroll
    for (int mi = 0; mi < 4; ++mi) af[mi] = *(const short8*)(Ab + mi * 2048 + kc * 32);
#pragma unroll
    for (int ni = 0; ni < 4; ++ni) wf[ni] = *(const short8*)(Wb + ni * 2048 + kc * 32);
#pragma unroll
    for (int mi = 0; mi < 4; ++mi)
#pragma unroll
      for (int ni = 0; ni < 4; ++ni)
        acc[mi][ni] = __builtin_amdgcn_mfma_f32_16x16x32_bf16(
            af[mi], wf[ni], acc[mi][ni], 0, 0, 0);
  }

  __shared__ __align__(16) float Y[128 * 132];
#pragma unroll
  for (int mi = 0; mi < 4; ++mi)
#pragma unroll
    for (int ni = 0; ni < 4; ++ni) {
      int col = wn * 64 + ni * 16 + r;
      float bia = bias[col];
#pragma unroll
      for (int reg = 0; reg < 4; ++reg) {
        int row = wm * 64 + mi * 16 + 4 * lg + reg;
        Y[row * 132 + col] =
            acc[mi][ni][reg] + bia + resf[(size_t)(m0 + row) * 128 + col];
      }
    }
  __syncthreads();
  const int rr = tid >> 1, qq = tid & 1;
  float sum = 0.f, sum2 = 0.f;
  float4 yv[16];
#pragma unroll
  for (int c = 0; c < 16; ++c) {
    float4 y = *(const float4*)&Y[rr * 132 + qq * 64 + c * 4];
    yv[c] = y;
    sum += y.x + y.y + y.z + y.w;
    sum2 += y.x * y.x + y.y * y.y + y.z * y.z + y.w * y.w;
  }
  sum += __shfl_xor(sum, 1);
  sum2 += __shfl_xor(sum2, 1);
  const float mean = sum * (1.f / 128.f);
  const float var = sum2 * (1.f / 128.f) - mean * mean;
  const float rstd = rsqrtf(var + 1e-5f);
#pragma unroll
  for (int c = 0; c < 16; ++c) {
    float4 gv = ((const float4*)gam)[qq * 16 + c];
    float4 bv = ((const float4*)bet)[qq * 16 + c];
    float4 y = yv[c];
    y.x = (y.x - mean) * rstd * gv.x + bv.x;
    y.y = (y.y - mean) * rstd * gv.y + bv.y;
    y.z = (y.z - mean) * rstd * gv.z + bv.z;
    y.w = (y.w - mean) * rstd * gv.w + bv.w;
    ((float4*)outf)[(size_t)(m0 + rr) * 32 + qq * 16 + c] = y;
    *(ushort4*)&outb[(size_t)(m0 + rr) * 128 + qq * 64 + c * 4] =
        make_ushort4(f2b(y.x), f2b(y.y), f2b(y.z), f2b(y.w));
  }
}

// ---------------------------------------------------------------------------
// Fused FFN, register-direct (unchanged).
// ---------------------------------------------------------------------------
__global__ __launch_bounds__(256, 2) void k_ffn_reg(
    const unsigned short* __restrict__ x, const unsigned short* __restrict__ w1b,
    const float* __restrict__ b1, const unsigned short* __restrict__ w2b,
    const float* __restrict__ b2, const float* __restrict__ gam,
    const float* __restrict__ bet, float* __restrict__ featf,
    unsigned short* __restrict__ featb) {
  __shared__ __align__(16) unsigned short hs[64 * 72];
  __shared__ __align__(16) float Y[64 * 132];
  const int tid = threadIdx.x;
  const int m0 = blockIdx.x * 64;
  const int lane = tid & 63, w = tid >> 6;
  const int wm = w >> 1, wn = w & 1;
  const int lg = lane >> 4, r = lane & 15;

  f32x4 accO[2][4];
#pragma unroll
  for (int mi = 0; mi < 2; ++mi)
#pragma unroll
    for (int ni = 0; ni < 4; ++ni) accO[mi][ni] = (f32x4){0.f, 0.f, 0.f, 0.f};

  const unsigned short* xb = x + (size_t)(m0 + wm * 32 + r) * 128 + lg * 8;
  const unsigned short* w2p = w2b + (size_t)(wn * 64 + r) * 512 + lg * 8;
  const unsigned short* hp = &hs[(wm * 32 + r) * 72 + lg * 8];

  for (int cc = 0; cc < 8; ++cc) {
    f32x4 accH[2][2];
#pragma unroll
    for (int mi = 0; mi < 2; ++mi)
#pragma unroll
      for (int ni = 0; ni < 2; ++ni) accH[mi][ni] = (f32x4){0.f, 0.f, 0.f, 0.f};
    const unsigned short* w1p =
        w1b + (size_t)(cc * 64 + wn * 32 + r) * 128 + lg * 8;
#pragma unroll
    for (int kc = 0; kc < 4; ++kc) {
      short8 af[2], wf[2];
#pragma unroll
      for (int mi = 0; mi < 2; ++mi) af[mi] = *(const short8*)(xb + mi * 2048 + kc * 32);
#pragma unroll
      for (int ni = 0; ni < 2; ++ni) wf[ni] = *(const short8*)(w1p + ni * 2048 + kc * 32);
#pragma unroll
      for (int mi = 0; mi < 2; ++mi)
#pragma unroll
        for (int ni = 0; ni < 2; ++ni)
          accH[mi][ni] = __builtin_amdgcn_mfma_f32_16x16x32_bf16(
              af[mi], wf[ni], accH[mi][ni], 0, 0, 0);
    }
    __syncthreads();
#pragma unroll
    for (int ni = 0; ni < 2; ++ni) {
      int n = wn * 32 + ni * 16 + r;
      float bv = b1[cc * 64 + n];
#pragma unroll
      for (int mi = 0; mi < 2; ++mi)
#pragma unroll
        for (int g = 0; g < 4; ++g) {
          int m = wm * 32 + mi * 16 + 4 * lg + g;
          hs[m * 72 + n] = f2b(fmaxf(accH[mi][ni][g] + bv, 0.f));
        }
    }
    __syncthreads();
#pragma unroll
    for (int kc2 = 0; kc2 < 2; ++kc2) {
      short8 af[2], wf[4];
#pragma unroll
      for (int mi = 0; mi < 2; ++mi) af[mi] = *(const short8*)(hp + mi * 1152 + kc2 * 32);
#pragma unroll
      for (int ni = 0; ni < 4; ++ni)
        wf[ni] = *(const short8*)(w2p + ni * 8192 + cc * 64 + kc2 * 32);
#pragma unroll
      for (int mi = 0; mi < 2; ++mi)
#pragma unroll
        for (int ni = 0; ni < 4; ++ni)
          accO[mi][ni] = __builtin_amdgcn_mfma_f32_16x16x32_bf16(
              af[mi], wf[ni], accO[mi][ni], 0, 0, 0);
    }
  }
#pragma unroll
  for (int mi = 0; mi < 2; ++mi)
#pragma unroll
    for (int ni = 0; ni < 4; ++ni) {
      int col = wn * 64 + ni * 16 + r;
      float bv = b2[col];
#pragma unroll
      for (int g = 0; g < 4; ++g) {
        int row = wm * 32 + mi * 16 + 4 * lg + g;
        Y[row * 132 + col] =
            accO[mi][ni][g] + bv + featf[(size_t)(m0 + row) * 128 + col];
      }
    }
  __syncthreads();
  const int rr = tid >> 2, qq = tid & 3;
  float sum = 0.f, sum2 = 0.f;
  float4 yv[8];
#pragma unroll
  for (int c = 0; c < 8; ++c) {
    float4 y = *(const float4*)&Y[rr * 132 + qq * 32 + c * 4];
    yv[c] = y;
    sum += y.x + y.y + y.z + y.w;
    sum2 += y.x * y.x + y.y * y.y + y.z * y.z + y.w * y.w;
  }
  sum += __shfl_xor(sum, 1); sum += __shfl_xor(sum, 2);
  sum2 += __shfl_xor(sum2, 1); sum2 += __shfl_xor(sum2, 2);
  const float mean = sum * (1.f / 128.f);
  const float var = sum2 * (1.f / 128.f) - mean * mean;
  const float rstd = rsqrtf(var + 1e-5f);
#pragma unroll
  for (int c = 0; c < 8; ++c) {
    float4 gv = ((const float4*)gam)[qq * 8 + c];
    float4 bv = ((const float4*)bet)[qq * 8 + c];
    float4 y = yv[c];
    y.x = (y.x - mean) * rstd * gv.x + bv.x;
    y.y = (y.y - mean) * rstd * gv.y + bv.y;
    y.z = (y.z - mean) * rstd * gv.z + bv.z;
    y.w = (y.w - mean) * rstd * gv.w + bv.w;
    ((float4*)featf)[(size_t)(m0 + rr) * 32 + qq * 8 + c] = y;
    *(ushort4*)&featb[(size_t)(m0 + rr) * 128 + qq * 32 + c * 4] =
        make_ushort4(f2b(y.x), f2b(y.y), f2b(y.z), f2b(y.w));
  }
}

// ---------------------------------------------------------------------------
// Final projection (DIM -> 2) + softmax.
// ---------------------------------------------------------------------------
__global__ void k_final(const float* __restrict__ feat, const float* __restrict__ pw,
                        const float* __restrict__ pb, float* __restrict__ out) {
  const int tid = threadIdx.x;
  const int tokb = blockIdx.x * 64 + (tid >> 2);
  const int qq = tid & 3;
  float d0 = 0.f, d1 = 0.f;
#pragma unroll
  for (int c = 0; c < 8; ++c) {
    float4 xv = ((const float4*)feat)[tokb * 32 + qq * 8 + c];
    float4 w0 = ((const float4*)pw)[qq * 8 + c];
    float4 w1 = ((const float4*)pw)[32 + qq * 8 + c];
    d0 += xv.x * w0.x + xv.y * w0.y + xv.z * w0.z + xv.w * w0.w;
    d1 += xv.x * w1.x + xv.y * w1.y + xv.z * w1.z + xv.w * w1.w;
  }
  d0 += __shfl_xor(d0, 1); d0 += __shfl_xor(d0, 2);
  d1 += __shfl_xor(d1, 1); d1 += __shfl_xor(d1, 2);
  if (qq == 0) {
    float l0 = d0 + pb[0], l1 = d1 + pb[1];
    float mx = fmaxf(l0, l1);
    float e0 = __expf(l0 - mx), e1 = __expf(l1 - mx);
    float inv = 1.f / (e0 + e1);
    ((float2*)out)[tokb] = make_float2(e0 * inv, e1 * inv);
  }
}

// ---------------------------------------------------------------------------
extern "C" void kernel_launch(void* const* d_in, const int* in_sizes, int n_in,
                              void* d_out, int out_size, void* d_ws, size_t ws_size,
                              hipStream_t stream) {
  const int* tok     = (const int*)d_in[0];
  const int* npad    = (const int*)d_in[1];
  const int* picked  = (const int*)d_in[2];
  const int* skipped = (const int*)d_in[3];
  const int* nupg    = (const int*)d_in[4];
  const float* emb   = (const float*)d_in[5];
  const float* inw   = (const float*)d_in[6];
  const float* inb   = (const float*)d_in[7];
  const float* outw  = (const float*)d_in[8];
  const float* outb_ = (const float*)d_in[9];
  const float* g1    = (const float*)d_in[10];
  const float* b1    = (const float*)d_in[11];
  const float* ffw1  = (const float*)d_in[12];
  const float* ffb1  = (const float*)d_in[13];
  const float* ffw2  = (const float*)d_in[14];
  const float* ffb2  = (const float*)d_in[15];
  const float* g2    = (const float*)d_in[16];
  const float* b2    = (const float*)d_in[17];
  const float* pw    = (const float*)d_in[18];
  const float* pb    = (const float*)d_in[19];

  char* wsb = (char*)d_ws;
  float*          featf = (float*)(wsb);                       // 16 MB
  unsigned short* qb    = (unsigned short*)(wsb + 16777216);   // 8 MB
  unsigned short* kbuf  = (unsigned short*)(wsb + 25165824);   // 8 MB
  unsigned short* vtb   = (unsigned short*)(wsb + 33554432);   // 8 MB
  unsigned short* featb = (unsigned short*)(wsb + 41943040);   // 8 MB
  unsigned short* obufb = (unsigned short*)(wsb + 50331648);   // 8 MB
  unsigned short* wqkvb = (unsigned short*)(wsb + 58720256);   // 384 KB
  unsigned short* woutb = (unsigned short*)(wsb + 59113472);   // 128 KB
  unsigned short* wff1b = (unsigned short*)(wsb + 59244544);   // 512 KB
  unsigned short* wff2b = (unsigned short*)(wsb + 59768832);   // 512 KB

  k_cvt_all<<<dim3(768), 256, 0, stream>>>(inw, outw, ffw1, ffw2,
                                           wqkvb, woutb, wff1b, wff2b);

  k_embed<<<dim3(CB * CS * 32 / 256), 256, 0, stream>>>(
      tok, picked, skipped, nupg, emb, featf, featb);

  for (int l = 0; l < CL; ++l) {
    k_gemm_qkv<<<dim3(256, 3), 256, 0, stream>>>(
        featb, wqkvb + (size_t)l * 49152, inb + (size_t)l * 384, qb, kbuf, vtb);
    k_attn2<<<dim3(CB * CH), 512, 0, stream>>>(
        qb, kbuf, vtb, npad, picked, skipped, obufb);
    k_gemm_ln<<<dim3(256), 256, 0, stream>>>(
        obufb, woutb + (size_t)l * 16384, outb_ + (size_t)l * 128,
        featf, featb, featf, g1 + (size_t)l * 128, b1 + (size_t)l * 128);
    k_ffn_reg<<<dim3(512), 256, 0, stream>>>(
        featb, wff1b + (size_t)l * 65536, ffb1 + (size_t)l * 512,
        wff2b + (size_t)l * 65536, ffb2 + (size_t)l * 128,
        g2 + (size_t)l * 128, b2 + (size_t)l * 128, featf, featb);
  }

  k_final<<<dim3(CB * CS / 64), 256, 0, stream>>>(featf, pw, pb, (float*)d_out);
}